// Round 4
// baseline (407.964 us; speedup 1.0000x reference)
//
#include <hip/hip_runtime.h>
#include <hip/hip_bf16.h>

// PIPNet interface scorer: out[p] = W2 . relu(W1 . concat(g1[il[p]], g2[ir[p]]) + b1) + b2
// R2: coalesced cooperative gather (16 lanes / 256B row).
// R3: pre-convert g1/g2 to bf16 in ws -> gather reads 128B rows, L3-resident.
//     Verified: main 335 -> 105 us, FETCH = compulsory 125 MB. But two
//     grid-stride cvt kernels cost ~280 us (latency-serialized loop).
// R5: (a) ONE fused prep kernel (W1 frags + both converts), 2 independent
//     chunks/thread, nontemporal f32 loads (don't evict bf16 from L2/L3).
//     (b) main LDS 34816->32768 B exact via XOR-swizzled 16B granules
//     (phys = g16 ^ (pair&7)) -> 5 blocks/CU instead of 4.
// R6 FIX: __builtin_nontemporal_load needs a clang ext_vector pointer, not
//     HIP_vector_type (uint4 is a struct). Use u32x4 ext_vector_type.

typedef __bf16 bf16x8 __attribute__((ext_vector_type(8)));
typedef float f32x16 __attribute__((ext_vector_type(16)));
typedef unsigned u32x4 __attribute__((ext_vector_type(4)));

__device__ __forceinline__ unsigned f2bf(float f) {
  union { float f; unsigned u; } v;
  v.f = f;
  unsigned u = v.u;
  return (u + 0x7fffu + ((u >> 16) & 1u)) >> 16;  // RNE f32->bf16
}
__device__ __forceinline__ unsigned u2bf(unsigned u) {
  return (u + 0x7fffu + ((u >> 16) & 1u)) >> 16;
}
__device__ __forceinline__ unsigned pack2(unsigned lo, unsigned hi) {
  return u2bf(lo) | (u2bf(hi) << 16);
}

// Fused prep: threads [0,2048) additionally build W1 bf16 B-fragments
// (layout for v_mfma_f32_32x32x16_bf16: frag (ks,nt,lane): n=lane&31,
// h=lane>>5; elems = W1[nt*32+n][ks*16+h*8+j], j=0..7). All threads then
// convert 2 chunks of 8 f32 -> 8 bf16 (g1 first, then g2).
__global__ __launch_bounds__(256) void prep_kernel(
    const float* __restrict__ g1, const float* __restrict__ g2,
    const float* __restrict__ W1,
    unsigned short* __restrict__ g1b, unsigned short* __restrict__ g2b,
    uint4* __restrict__ w1f, int n8_1, int n8_2) {
  const int t = blockIdx.x * 256 + threadIdx.x;

  if (t < 2048) {
    int lane = t & 63;
    int nt = (t >> 6) & 3;
    int ks = t >> 8;
    int n = lane & 31, h = lane >> 5;
    const float4* src =
        (const float4*)(W1 + ((nt * 32 + n) * 128 + ks * 16 + h * 8));
    float4 a = src[0], b = src[1];
    uint4 o;
    o.x = f2bf(a.x) | (f2bf(a.y) << 16);
    o.y = f2bf(a.z) | (f2bf(a.w) << 16);
    o.z = f2bf(b.x) | (f2bf(b.y) << 16);
    o.w = f2bf(b.z) | (f2bf(b.w) << 16);
    w1f[t] = o;
  }

  const int total = n8_1 + n8_2;
  const int c0 = t * 2;
#pragma unroll
  for (int u = 0; u < 2; ++u) {
    int c = c0 + u;
    if (c < total) {
      const float* src;
      unsigned short* dst;
      int lc;
      if (c < n8_1) { src = g1; dst = g1b; lc = c; }
      else          { src = g2; dst = g2b; lc = c - n8_1; }
      const u32x4* sp = (const u32x4*)(src + (size_t)lc * 8);
      u32x4 a = __builtin_nontemporal_load(sp);      // read-once: don't cache
      u32x4 b = __builtin_nontemporal_load(sp + 1);
      u32x4 o;
      o.x = pack2(a.x, a.y);
      o.y = pack2(a.z, a.w);
      o.z = pack2(b.x, b.y);
      o.w = pack2(b.z, b.w);
      *(u32x4*)(dst + (size_t)lc * 8) = o;           // regular: keep in L2/L3
    }
  }
}

// LDS: 128 rows x 256 B = 32768 B exactly -> 5 blocks/CU. Bank dispersion via
// XOR swizzle of 16B granules: phys_granule = logical_granule ^ (row & 7).
// Applied identically on gather-write and compute-read.
template <bool BF16G>
__global__ __launch_bounds__(256, 5) void pip_main_kernel(
    const float* __restrict__ g1, const float* __restrict__ g2,
    const unsigned short* __restrict__ g1b,
    const unsigned short* __restrict__ g2b,
    const int* __restrict__ il, const int* __restrict__ ir,
    const bf16x8* __restrict__ w1f,
    const float* __restrict__ b1, const float* __restrict__ w2,
    const float* __restrict__ b2,
    float* __restrict__ out, int P) {
  __shared__ unsigned char A[128 * 256];  // 32768 B

  const int t = threadIdx.x;
  const int lane = t & 63;
  const int w = t >> 6;
  const int pair0 = blockIdx.x * 128;

  if (BF16G) {
    // bf16 gather: 8 lanes per (pair,side) row of 64 bf16 (128B).
    // r = j*32 + w*8 + g, g = lane>>3; side = g&1 fixed; pair = j*16+(w*8+g)>>1
    const int sub = lane & 7;            // 16B slice in the 128B half-row
    const int g = lane >> 3;
    const int side = g & 1;
    const int pairB = (w * 8 + g) >> 1;  // 0..15
    const unsigned short* feat = side ? g2b : g1b;
    const int* idxarr = side ? ir : il;

    int idxv[8];
#pragma unroll
    for (int j = 0; j < 8; ++j) {
      int gp = pair0 + j * 16 + pairB;
      int pidx = (gp < P) ? gp : (P - 1);
      idxv[j] = idxarr[pidx];
    }
#pragma unroll
    for (int j = 0; j < 8; ++j) {
      int pair = j * 16 + pairB;
      uint4 v = *(const uint4*)(feat + (size_t)idxv[j] * 64 + sub * 8);
      int g16 = side * 8 + sub;
      *(uint4*)(&A[pair * 256 + ((g16 ^ (pair & 7)) << 4)]) = v;
    }
  } else {
    // f32 fallback (verified structure): 16 lanes per 256B feature row.
    const int sub = lane & 15;
    const int g = lane >> 4;
    const int side = g & 1;
    const int pairB = (w * 4 + g) >> 1;  // 0..7
    const float* feat = side ? g2 : g1;
    const int* idxarr = side ? ir : il;

    int idxv[16];
#pragma unroll
    for (int j = 0; j < 16; ++j) {
      int gp = pair0 + j * 8 + pairB;
      int pidx = (gp < P) ? gp : (P - 1);
      idxv[j] = idxarr[pidx];
    }
#pragma unroll
    for (int j = 0; j < 16; ++j) {
      int pair = j * 8 + pairB;
      float4 v = *(const float4*)(feat + (size_t)idxv[j] * 64 + sub * 4);
      unsigned lo = f2bf(v.x) | (f2bf(v.y) << 16);
      unsigned hi = f2bf(v.z) | (f2bf(v.w) << 16);
      int g16 = side * 8 + (sub >> 1);
      *(uint2*)(&A[pair * 256 + ((g16 ^ (pair & 7)) << 4) + ((sub & 1) << 3)]) =
          make_uint2(lo, hi);
    }
  }
  __syncthreads();

  // Compute: wave w handles pairs [w*32, w*32+32), full n = 0..127.
  const int n = lane & 31;
  const int h = lane >> 5;

  f32x16 acc[4];
#pragma unroll
  for (int nt = 0; nt < 4; ++nt)
#pragma unroll
    for (int i = 0; i < 16; ++i) acc[nt][i] = 0.0f;

  const unsigned char* Abase = &A[(w * 32 + n) * 256];
  const int rk = n & 7;  // (w*32+n)&7
#pragma unroll
  for (int ks = 0; ks < 8; ++ks) {
    bf16x8 af = *(const bf16x8*)(Abase + (((ks * 2 + h) ^ rk) << 4));
#pragma unroll
    for (int nt = 0; nt < 4; ++nt) {
      bf16x8 bfr = w1f[(ks * 4 + nt) * 64 + lane];
      acc[nt] = __builtin_amdgcn_mfma_f32_32x32x16_bf16(af, bfr, acc[nt], 0, 0, 0);
    }
  }

  // Epilogue: out[p] = sum_n relu(acc + b1[n]) * w2[n] + b2.
  // C/D layout: col(n) = lane&31 (+32*nt), row(m) = (r&3) + 8*(r>>2) + 4*h.
  float b1v[4], w2v[4];
#pragma unroll
  for (int nt = 0; nt < 4; ++nt) {
    b1v[nt] = b1[nt * 32 + n];
    w2v[nt] = w2[nt * 32 + n];
  }
  const float bias2 = b2[0];

#pragma unroll
  for (int r = 0; r < 16; ++r) {
    float s = 0.0f;
#pragma unroll
    for (int nt = 0; nt < 4; ++nt) {
      float v = acc[nt][r] + b1v[nt];
      v = fmaxf(v, 0.0f);
      s = fmaf(v, w2v[nt], s);
    }
    s += __shfl_xor(s, 1);
    s += __shfl_xor(s, 2);
    s += __shfl_xor(s, 4);
    s += __shfl_xor(s, 8);
    s += __shfl_xor(s, 16);
    if (n == 0) {
      int row = (r & 3) + 8 * (r >> 2) + 4 * h;
      int gp = pair0 + w * 32 + row;
      if (gp < P) out[gp] = s + bias2;
    }
  }
}

extern "C" void kernel_launch(void* const* d_in, const int* in_sizes, int n_in,
                              void* d_out, int out_size, void* d_ws, size_t ws_size,
                              hipStream_t stream) {
  const float* g1 = (const float*)d_in[0];   // graph1_x [N,64] f32
  const float* g2 = (const float*)d_in[1];   // graph2_x [N,64] f32
  const int* il = (const int*)d_in[2];       // idx_left [P] int32
  const int* ir = (const int*)d_in[3];       // idx_right [P] int32
  const float* W1 = (const float*)d_in[4];   // [128,128]
  const float* b1 = (const float*)d_in[5];   // [128]
  const float* w2 = (const float*)d_in[6];   // [1,128]
  const float* b2 = (const float*)d_in[7];   // [1]
  float* out = (float*)d_out;                // [P,1] f32
  const int P = out_size;                    // element count

  // in_sizes is ELEMENT counts: N*64 floats per graph.
  const int N1 = in_sizes[0] / 64;
  const int N2 = in_sizes[1] / 64;

  const size_t frag_bytes = 32 * 1024;
  const size_t g1b_bytes = (size_t)N1 * 64 * 2;
  const size_t g2b_bytes = (size_t)N2 * 64 * 2;
  const bool bf16path =
      N1 > 0 && N2 > 0 && ws_size >= frag_bytes + g1b_bytes + g2b_bytes;

  unsigned short* g1b = (unsigned short*)((char*)d_ws + frag_bytes);
  unsigned short* g2b = g1b + (size_t)N1 * 64;

  const int n8_1 = bf16path ? N1 * 8 : 0;
  const int n8_2 = bf16path ? N2 * 8 : 0;
  const int total = n8_1 + n8_2;
  int prep_blocks = ((total + 1) / 2 + 255) / 256;
  if (prep_blocks < 8) prep_blocks = 8;  // always cover the 2048 W1 threads
  prep_kernel<<<prep_blocks, 256, 0, stream>>>(g1, g2, W1, g1b, g2b,
                                               (uint4*)d_ws, n8_1, n8_2);

  const int nblocks = (P + 127) / 128;
  if (bf16path) {
    pip_main_kernel<true><<<nblocks, 256, 0, stream>>>(
        g1, g2, g1b, g2b, il, ir, (const bf16x8*)d_ws, b1, w2, b2, out, P);
  } else {
    pip_main_kernel<false><<<nblocks, 256, 0, stream>>>(
        g1, g2, nullptr, nullptr, il, ir, (const bf16x8*)d_ws, b1, w2, b2,
        out, P);
  }
}

// Round 5
// 360.691 us; speedup vs baseline: 1.1311x; 1.1311x over previous
//
#include <hip/hip_runtime.h>
#include <hip/hip_bf16.h>

// PIPNet interface scorer: out[p] = W2 . relu(W1 . concat(g1[il[p]], g2[ir[p]]) + b1) + b2
// R3: pre-convert g1/g2 to bf16 in ws -> gather reads 128B rows; main 335->105us.
// R5: fused prep (W1 frags + both converts) + main LDS 32768B XOR-swizzled,
//     5 blocks/CU. Measured: prep 122us @ 3.1 TB/s (39% peak) -- thread-owns-
//     64B layout made each load instruction touch 64 cache lines at 25% util.
// R7: wave-cooperative prep addressing: wave owns 4KB, lane i reads
//     base + j*1024 + i*16 (contiguous 1KB per instruction), 4 nt-loads in
//     flight/thread, 8B/lane contiguous stores. Main unchanged from R5.

typedef __bf16 bf16x8 __attribute__((ext_vector_type(8)));
typedef float f32x16 __attribute__((ext_vector_type(16)));
typedef unsigned u32x4 __attribute__((ext_vector_type(4)));
typedef unsigned u32x2 __attribute__((ext_vector_type(2)));

__device__ __forceinline__ unsigned f2bf(float f) {
  union { float f; unsigned u; } v;
  v.f = f;
  unsigned u = v.u;
  return (u + 0x7fffu + ((u >> 16) & 1u)) >> 16;  // RNE f32->bf16
}
__device__ __forceinline__ unsigned u2bf(unsigned u) {
  return (u + 0x7fffu + ((u >> 16) & 1u)) >> 16;
}
__device__ __forceinline__ unsigned pack2(unsigned lo, unsigned hi) {
  return u2bf(lo) | (u2bf(hi) << 16);
}

// Fused prep. Threads [0,2048) build W1 bf16 B-fragments (layout for
// v_mfma_f32_32x32x16_bf16: frag (ks,nt,lane): n=lane&31, h=lane>>5;
// elems = W1[nt*32+n][ks*16+h*8+j], j=0..7). All threads convert the
// concatenated g1|g2 f32 stream to bf16: chunk c = one 16B load / 8B store;
// wave W, round j, lane l handles c = W*256 + j*64 + l  (per-instruction
// contiguous 1KB loads / 512B stores).
__global__ __launch_bounds__(256) void prep_kernel(
    const float* __restrict__ g1, const float* __restrict__ g2,
    const float* __restrict__ W1,
    unsigned short* __restrict__ g1b, unsigned short* __restrict__ g2b,
    uint4* __restrict__ w1f, int n16_1, int n16_2) {
  const int t = blockIdx.x * 256 + threadIdx.x;

  if (t < 2048) {
    int lane = t & 63;
    int nt = (t >> 6) & 3;
    int ks = t >> 8;
    int n = lane & 31, h = lane >> 5;
    const float4* src =
        (const float4*)(W1 + ((nt * 32 + n) * 128 + ks * 16 + h * 8));
    float4 a = src[0], b = src[1];
    uint4 o;
    o.x = f2bf(a.x) | (f2bf(a.y) << 16);
    o.y = f2bf(a.z) | (f2bf(a.w) << 16);
    o.z = f2bf(b.x) | (f2bf(b.y) << 16);
    o.w = f2bf(b.z) | (f2bf(b.w) << 16);
    w1f[t] = o;
  }

  const int total = n16_1 + n16_2;
  const int Wv = t >> 6;     // global wave id
  const int lane = t & 63;
  const int cbase = Wv * 256 + lane;
#pragma unroll
  for (int j = 0; j < 4; ++j) {
    int c = cbase + j * 64;
    if (c < total) {
      const float* s;
      unsigned short* d;
      int lc;
      if (c < n16_1) { s = g1; d = g1b; lc = c; }
      else           { s = g2; d = g2b; lc = c - n16_1; }
      u32x4 a =
          __builtin_nontemporal_load((const u32x4*)(s + (size_t)lc * 4));
      u32x2 o;
      o.x = pack2(a.x, a.y);
      o.y = pack2(a.z, a.w);
      *(u32x2*)(d + (size_t)lc * 4) = o;  // 8B/lane, contiguous per instr
    }
  }
}

// LDS: 128 rows x 256 B = 32768 B exactly -> 5 blocks/CU. Bank dispersion via
// XOR swizzle of 16B granules: phys_granule = logical_granule ^ (row & 7).
// Applied identically on gather-write and compute-read.
template <bool BF16G>
__global__ __launch_bounds__(256, 5) void pip_main_kernel(
    const float* __restrict__ g1, const float* __restrict__ g2,
    const unsigned short* __restrict__ g1b,
    const unsigned short* __restrict__ g2b,
    const int* __restrict__ il, const int* __restrict__ ir,
    const bf16x8* __restrict__ w1f,
    const float* __restrict__ b1, const float* __restrict__ w2,
    const float* __restrict__ b2,
    float* __restrict__ out, int P) {
  __shared__ unsigned char A[128 * 256];  // 32768 B

  const int t = threadIdx.x;
  const int lane = t & 63;
  const int w = t >> 6;
  const int pair0 = blockIdx.x * 128;

  if (BF16G) {
    // bf16 gather: 8 lanes per (pair,side) row of 64 bf16 (128B).
    // r = j*32 + w*8 + g, g = lane>>3; side = g&1 fixed; pair = j*16+(w*8+g)>>1
    const int sub = lane & 7;            // 16B slice in the 128B half-row
    const int g = lane >> 3;
    const int side = g & 1;
    const int pairB = (w * 8 + g) >> 1;  // 0..15
    const unsigned short* feat = side ? g2b : g1b;
    const int* idxarr = side ? ir : il;

    int idxv[8];
#pragma unroll
    for (int j = 0; j < 8; ++j) {
      int gp = pair0 + j * 16 + pairB;
      int pidx = (gp < P) ? gp : (P - 1);
      idxv[j] = idxarr[pidx];
    }
#pragma unroll
    for (int j = 0; j < 8; ++j) {
      int pair = j * 16 + pairB;
      uint4 v = *(const uint4*)(feat + (size_t)idxv[j] * 64 + sub * 8);
      int g16 = side * 8 + sub;
      *(uint4*)(&A[pair * 256 + ((g16 ^ (pair & 7)) << 4)]) = v;
    }
  } else {
    // f32 fallback (verified structure): 16 lanes per 256B feature row.
    const int sub = lane & 15;
    const int g = lane >> 4;
    const int side = g & 1;
    const int pairB = (w * 4 + g) >> 1;  // 0..7
    const float* feat = side ? g2 : g1;
    const int* idxarr = side ? ir : il;

    int idxv[16];
#pragma unroll
    for (int j = 0; j < 16; ++j) {
      int gp = pair0 + j * 8 + pairB;
      int pidx = (gp < P) ? gp : (P - 1);
      idxv[j] = idxarr[pidx];
    }
#pragma unroll
    for (int j = 0; j < 16; ++j) {
      int pair = j * 8 + pairB;
      float4 v = *(const float4*)(feat + (size_t)idxv[j] * 64 + sub * 4);
      unsigned lo = f2bf(v.x) | (f2bf(v.y) << 16);
      unsigned hi = f2bf(v.z) | (f2bf(v.w) << 16);
      int g16 = side * 8 + (sub >> 1);
      *(uint2*)(&A[pair * 256 + ((g16 ^ (pair & 7)) << 4) + ((sub & 1) << 3)]) =
          make_uint2(lo, hi);
    }
  }
  __syncthreads();

  // Compute: wave w handles pairs [w*32, w*32+32), full n = 0..127.
  const int n = lane & 31;
  const int h = lane >> 5;

  f32x16 acc[4];
#pragma unroll
  for (int nt = 0; nt < 4; ++nt)
#pragma unroll
    for (int i = 0; i < 16; ++i) acc[nt][i] = 0.0f;

  const unsigned char* Abase = &A[(w * 32 + n) * 256];
  const int rk = n & 7;  // (w*32+n)&7
#pragma unroll
  for (int ks = 0; ks < 8; ++ks) {
    bf16x8 af = *(const bf16x8*)(Abase + (((ks * 2 + h) ^ rk) << 4));
#pragma unroll
    for (int nt = 0; nt < 4; ++nt) {
      bf16x8 bfr = w1f[(ks * 4 + nt) * 64 + lane];
      acc[nt] = __builtin_amdgcn_mfma_f32_32x32x16_bf16(af, bfr, acc[nt], 0, 0, 0);
    }
  }

  // Epilogue: out[p] = sum_n relu(acc + b1[n]) * w2[n] + b2.
  // C/D layout: col(n) = lane&31 (+32*nt), row(m) = (r&3) + 8*(r>>2) + 4*h.
  float b1v[4], w2v[4];
#pragma unroll
  for (int nt = 0; nt < 4; ++nt) {
    b1v[nt] = b1[nt * 32 + n];
    w2v[nt] = w2[nt * 32 + n];
  }
  const float bias2 = b2[0];

#pragma unroll
  for (int r = 0; r < 16; ++r) {
    float s = 0.0f;
#pragma unroll
    for (int nt = 0; nt < 4; ++nt) {
      float v = acc[nt][r] + b1v[nt];
      v = fmaxf(v, 0.0f);
      s = fmaf(v, w2v[nt], s);
    }
    s += __shfl_xor(s, 1);
    s += __shfl_xor(s, 2);
    s += __shfl_xor(s, 4);
    s += __shfl_xor(s, 8);
    s += __shfl_xor(s, 16);
    if (n == 0) {
      int row = (r & 3) + 8 * (r >> 2) + 4 * h;
      int gp = pair0 + w * 32 + row;
      if (gp < P) out[gp] = s + bias2;
    }
  }
}

extern "C" void kernel_launch(void* const* d_in, const int* in_sizes, int n_in,
                              void* d_out, int out_size, void* d_ws, size_t ws_size,
                              hipStream_t stream) {
  const float* g1 = (const float*)d_in[0];   // graph1_x [N,64] f32
  const float* g2 = (const float*)d_in[1];   // graph2_x [N,64] f32
  const int* il = (const int*)d_in[2];       // idx_left [P] int32
  const int* ir = (const int*)d_in[3];       // idx_right [P] int32
  const float* W1 = (const float*)d_in[4];   // [128,128]
  const float* b1 = (const float*)d_in[5];   // [128]
  const float* w2 = (const float*)d_in[6];   // [1,128]
  const float* b2 = (const float*)d_in[7];   // [1]
  float* out = (float*)d_out;                // [P,1] f32
  const int P = out_size;                    // element count

  // in_sizes is ELEMENT counts: N*64 floats per graph.
  const int N1 = in_sizes[0] / 64;
  const int N2 = in_sizes[1] / 64;

  const size_t frag_bytes = 32 * 1024;
  const size_t g1b_bytes = (size_t)N1 * 64 * 2;
  const size_t g2b_bytes = (size_t)N2 * 64 * 2;
  const bool bf16path =
      N1 > 0 && N2 > 0 && ws_size >= frag_bytes + g1b_bytes + g2b_bytes;

  unsigned short* g1b = (unsigned short*)((char*)d_ws + frag_bytes);
  unsigned short* g2b = g1b + (size_t)N1 * 64;

  // 16B chunks per graph (N*64 floats / 4 floats-per-chunk = N*16).
  const int n16_1 = bf16path ? N1 * 16 : 0;
  const int n16_2 = bf16path ? N2 * 16 : 0;
  const int total = n16_1 + n16_2;
  int prep_blocks = (total + 1023) / 1024;  // 256 thr * 4 chunks = 1024/block
  if (prep_blocks < 8) prep_blocks = 8;     // always cover the 2048 W1 threads
  prep_kernel<<<prep_blocks, 256, 0, stream>>>(g1, g2, W1, g1b, g2b,
                                               (uint4*)d_ws, n16_1, n16_2);

  const int nblocks = (P + 127) / 128;
  if (bf16path) {
    pip_main_kernel<true><<<nblocks, 256, 0, stream>>>(
        g1, g2, g1b, g2b, il, ir, (const bf16x8*)d_ws, b1, w2, b2, out, P);
  } else {
    pip_main_kernel<false><<<nblocks, 256, 0, stream>>>(
        g1, g2, nullptr, nullptr, il, ir, (const bf16x8*)d_ws, b1, w2, b2,
        out, P);
  }
}

// Round 6
// 342.422 us; speedup vs baseline: 1.1914x; 1.0534x over previous
//
#include <hip/hip_runtime.h>

// PIPNet interface scorer: out[p] = W2 . relu(W1 . concat(g1[il[p]], g2[ir[p]]) + b1) + b2
// R3-R5 arc: bf16 pre-convert cut main 335->100us, BUT wall-time accounting
// across R2/R4/R5 + session-1 baseline shows a ~160us cost proportional to
// ws_size (~1.25us/MB; harness re-poisons the workspace every iteration).
// The 128MB ws costs more than the pre-convert saves.
// R6: drop the big ws (back to 32KB W1 frags only). f32-direct main with:
//   - per-wave-private LDS gather regions (8KB/wave) -> NO __syncthreads;
//     per-wave s_waitcnt lgkmcnt(0) only; waves slip independently.
//   - 16 idx preloads + 16 independent float4 gather loads in flight/thread.
//   - f32->bf16 RNE convert on LDS write (identical numerics to verified R5).
//   - LDS layout/swizzle/compute/epilogue byte-identical to R5-verified code.

typedef __bf16 bf16x8 __attribute__((ext_vector_type(8)));
typedef float f32x16 __attribute__((ext_vector_type(16)));

__device__ __forceinline__ unsigned f2bf(float f) {
  union { float f; unsigned u; } v;
  v.f = f;
  unsigned u = v.u;
  return (u + 0x7fffu + ((u >> 16) & 1u)) >> 16;  // RNE f32->bf16
}

// W1 [128x128] f32 row-major -> bf16 B-fragments for v_mfma_f32_32x32x16_bf16.
// Fragment (ks, nt, lane): n = lane&31, h = lane>>5;
//   elements = W1[nt*32+n][ks*16 + h*8 + j], j = 0..7
__global__ __launch_bounds__(256) void w1_frag_kernel(
    const float* __restrict__ W1, uint4* __restrict__ w1f) {
  int t = blockIdx.x * 256 + threadIdx.x;  // 0..2047
  int lane = t & 63;
  int nt = (t >> 6) & 3;
  int ks = t >> 8;
  int n = lane & 31, h = lane >> 5;
  const float4* src =
      (const float4*)(W1 + ((nt * 32 + n) * 128 + ks * 16 + h * 8));
  float4 a = src[0], b = src[1];
  uint4 o;
  o.x = f2bf(a.x) | (f2bf(a.y) << 16);
  o.y = f2bf(a.z) | (f2bf(a.w) << 16);
  o.z = f2bf(b.x) | (f2bf(b.y) << 16);
  o.w = f2bf(b.z) | (f2bf(b.w) << 16);
  w1f[t] = o;
}

// LDS: 4 waves x 8192 B (32 local pairs x 256 B). Within a wave's region the
// byte layout is identical to the R5-verified kernel: row pl holds the 128
// bf16 concat features, stored as 16B granules at phys = (g16 ^ (pl&7))<<4.
__global__ __launch_bounds__(256, 5) void pip_main_kernel(
    const float* __restrict__ g1, const float* __restrict__ g2,
    const int* __restrict__ il, const int* __restrict__ ir,
    const bf16x8* __restrict__ w1f,
    const float* __restrict__ b1, const float* __restrict__ w2,
    const float* __restrict__ b2,
    float* __restrict__ out, int P) {
  __shared__ unsigned char A[4][8192];  // 32768 B total -> 5 blocks/CU

  const int t = threadIdx.x;
  const int lane = t & 63;
  const int w = t >> 6;
  const int pair0 = blockIdx.x * 128;

  // ---- Per-wave gather: 16 lanes per 256B f32 row; 16 rounds cover the
  // wave's 64 rows (32 pairs x 2 sides). Round j, group g = lane>>4:
  // row r = j*4 + g; side = r&1 = g&1 (fixed); local pair = j*2 + (g>>1).
  const int sub = lane & 15;     // lane's 16B f32 slice within the 256B row
  const int g = lane >> 4;       // 0..3
  const int side = g & 1;        // 0: left/g1, 1: right/g2
  const int phalf = g >> 1;      // 0..1
  const float* feat = side ? g2 : g1;
  const int* idxarr = side ? ir : il;

  int idxv[16];
#pragma unroll
  for (int j = 0; j < 16; ++j) {
    int gp = pair0 + w * 32 + j * 2 + phalf;
    int pidx = (gp < P) ? gp : (P - 1);
    idxv[j] = idxarr[pidx];
  }

  unsigned char* Aw = &A[w][0];
#pragma unroll
  for (int j = 0; j < 16; ++j) {
    int pl = j * 2 + phalf;  // local pair 0..31
    // 16 consecutive lanes read 256B contiguous => 64B-granular requests
    float4 v = *(const float4*)(feat + (size_t)idxv[j] * 64 + sub * 4);
    unsigned lo = f2bf(v.x) | (f2bf(v.y) << 16);
    unsigned hi = f2bf(v.z) | (f2bf(v.w) << 16);
    int g16 = side * 8 + (sub >> 1);  // logical 16B granule 0..15
    *(uint2*)(Aw + pl * 256 + ((g16 ^ (pl & 7)) << 4) + ((sub & 1) << 3)) =
        make_uint2(lo, hi);
  }
  // Wave-private region: only this wave reads what it wrote. No block
  // barrier needed; just drain this wave's LDS writes.
  asm volatile("s_waitcnt lgkmcnt(0)" ::: "memory");

  // ---- Compute: wave w handles pairs [w*32, w*32+32), full n = 0..127 ----
  const int n = lane & 31;   // MFMA m/n index within tile (= local pair)
  const int h = lane >> 5;

  f32x16 acc[4];
#pragma unroll
  for (int nt = 0; nt < 4; ++nt)
#pragma unroll
    for (int i = 0; i < 16; ++i) acc[nt][i] = 0.0f;

  const unsigned char* Abase = Aw + n * 256;
  const int rk = n & 7;  // = local pair & 7
#pragma unroll
  for (int ks = 0; ks < 8; ++ks) {
    bf16x8 af = *(const bf16x8*)(Abase + (((ks * 2 + h) ^ rk) << 4));
#pragma unroll
    for (int nt = 0; nt < 4; ++nt) {
      bf16x8 bfr = w1f[(ks * 4 + nt) * 64 + lane];
      acc[nt] = __builtin_amdgcn_mfma_f32_32x32x16_bf16(af, bfr, acc[nt], 0, 0, 0);
    }
  }

  // ---- Epilogue: out[p] = sum_n relu(acc + b1[n]) * w2[n] + b2 ----
  // C/D layout: col(n) = lane&31 (+32*nt), row(m) = (r&3) + 8*(r>>2) + 4*h.
  float b1v[4], w2v[4];
#pragma unroll
  for (int nt = 0; nt < 4; ++nt) {
    b1v[nt] = b1[nt * 32 + n];
    w2v[nt] = w2[nt * 32 + n];
  }
  const float bias2 = b2[0];

#pragma unroll
  for (int r = 0; r < 16; ++r) {
    float s = 0.0f;
#pragma unroll
    for (int nt = 0; nt < 4; ++nt) {
      float v = acc[nt][r] + b1v[nt];
      v = fmaxf(v, 0.0f);
      s = fmaf(v, w2v[nt], s);
    }
    s += __shfl_xor(s, 1);
    s += __shfl_xor(s, 2);
    s += __shfl_xor(s, 4);
    s += __shfl_xor(s, 8);
    s += __shfl_xor(s, 16);
    if (n == 0) {
      int row = (r & 3) + 8 * (r >> 2) + 4 * h;
      int gp = pair0 + w * 32 + row;
      if (gp < P) out[gp] = s + bias2;
    }
  }
}

extern "C" void kernel_launch(void* const* d_in, const int* in_sizes, int n_in,
                              void* d_out, int out_size, void* d_ws, size_t ws_size,
                              hipStream_t stream) {
  const float* g1 = (const float*)d_in[0];   // graph1_x [N,64] f32
  const float* g2 = (const float*)d_in[1];   // graph2_x [N,64] f32
  const int* il = (const int*)d_in[2];       // idx_left [P] int32
  const int* ir = (const int*)d_in[3];       // idx_right [P] int32
  const float* W1 = (const float*)d_in[4];   // [128,128]
  const float* b1 = (const float*)d_in[5];   // [128]
  const float* w2 = (const float*)d_in[6];   // [1,128]
  const float* b2 = (const float*)d_in[7];   // [1]
  float* out = (float*)d_out;                // [P,1] f32
  const int P = out_size;                    // element count

  // d_ws: only 32 KB of bf16 W1 B-fragments (rebuilt every call).
  w1_frag_kernel<<<8, 256, 0, stream>>>(W1, (uint4*)d_ws);

  const int nblocks = (P + 127) / 128;
  pip_main_kernel<<<nblocks, 256, 0, stream>>>(
      g1, g2, il, ir, (const bf16x8*)d_ws, b1, w2, b2, out, P);
}